// Round 6
// baseline (190.279 us; speedup 1.0000x reference)
//
#include <hip/hip_runtime.h>
#include <hip/hip_bf16.h>
#include <stdint.h>

#define T_ 2
#define N_ 4096
#define D_ 1024
#define E_ 8
#define O_ 1024

#define BM 128
#define BN 128
#define BK 64   // r14: 128-B LDS rows, 16 K-steps (was 32) -> half the barrier/drain events

typedef __attribute__((ext_vector_type(8))) short short8;
typedef __attribute__((ext_vector_type(4))) float f32x4;

#define AS1 __attribute__((address_space(1)))
#define AS3 __attribute__((address_space(3)))

// async global->LDS, 16B per lane; LDS dest = base + lane*16 (wave-uniform base)
__device__ inline void gld16(const unsigned short* g, unsigned short* l) {
    __builtin_amdgcn_global_load_lds((const AS1 unsigned int*)g,
                                     (AS3 unsigned int*)l, 16, 0, 0);
}

__device__ inline unsigned short f2bf(float f) {
    union { float f; unsigned u; } v; v.f = f;
    unsigned r = v.u + 0x7fff + ((v.u >> 16) & 1);  // RNE
    return (unsigned short)(r >> 16);
}

// ---------------------------------------------------------------------------
// Kernel 1 (fused): blocks 0..1023 = gating + x->bf16 (8 tokens/block);
// blocks 1024..2047 = We fp32 [e][d][o] -> bf16 packed
// [(e*8+o/128)*128+o%128][d].  Disjoint data; fused so pack's ~48MB of
// traffic runs concurrently with gate.
// ---------------------------------------------------------------------------
__global__ __launch_bounds__(256) void prep_kernel(
    const float* __restrict__ x, const float* __restrict__ Wg,
    const float* __restrict__ We,
    unsigned short* __restrict__ xb, unsigned short* __restrict__ Wbp,
    int* __restrict__ route, float2* __restrict__ gpair)
{
    __shared__ __align__(16) char smem[E_ * D_ * 4];   // 32 KB (gate); pack uses 17.4 KB
    int tid = threadIdx.x;

    if (blockIdx.x < 1024) {
        // ---- gate half ----
        float (*WgT)[D_] = (float(*)[D_])smem;
        int wave = tid >> 6, lane = tid & 63;
        int token0 = blockIdx.x * 8;
        int t = token0 >> 12;                 // 8 consecutive tokens share t
        const float* wgb = Wg + (size_t)t * D_ * E_;

#pragma unroll
        for (int r = 0; r < 8; ++r) {
            int f = r * 1024 + tid * 4;       // flat Wg index; (d=f>>3, e=f&7)
            float4 v = *(const float4*)(wgb + f);
            WgT[f & 7][f >> 3]             = v.x;
            WgT[(f + 1) & 7][(f + 1) >> 3] = v.y;
            WgT[(f + 2) & 7][(f + 2) >> 3] = v.z;
            WgT[(f + 3) & 7][(f + 3) >> 3] = v.w;
        }
        __syncthreads();

#pragma unroll
        for (int tl = 0; tl < 2; ++tl) {
            int token = token0 + wave * 2 + tl;
            const float* xrow = x + (size_t)token * D_;

            float4 xv[4];
#pragma unroll
            for (int c = 0; c < 4; ++c)
                xv[c] = *(const float4*)(xrow + c * 256 + lane * 4);

            float acc[E_] = {0.f, 0.f, 0.f, 0.f, 0.f, 0.f, 0.f, 0.f};
#pragma unroll
            for (int c = 0; c < 4; ++c) {
                int d0 = c * 256 + lane * 4;
                unsigned lo = f2bf(xv[c].x) | ((unsigned)f2bf(xv[c].y) << 16);
                unsigned hi = f2bf(xv[c].z) | ((unsigned)f2bf(xv[c].w) << 16);
                *(uint2*)(&xb[(size_t)token * D_ + d0]) = make_uint2(lo, hi);
#pragma unroll
                for (int e = 0; e < E_; ++e) {
                    float4 w = *(const float4*)(&WgT[e][d0]);
                    acc[e] += xv[c].x * w.x + xv[c].y * w.y + xv[c].z * w.z + xv[c].w * w.w;
                }
            }
#pragma unroll
            for (int off = 1; off < 64; off <<= 1) {
#pragma unroll
                for (int e = 0; e < E_; ++e) acc[e] += __shfl_xor(acc[e], off, 64);
            }

            if (lane == 0) {
                // top-2, lowest-index-first on ties (matches jax.lax.top_k)
                float best = acc[0]; int bi = 0;
#pragma unroll
                for (int e = 1; e < E_; ++e) if (acc[e] > best) { best = acc[e]; bi = e; }
                float sec = -INFINITY; int si = 0;
#pragma unroll
                for (int e = 0; e < E_; ++e) if (e != bi && acc[e] > sec) { sec = acc[e]; si = e; }
                float s = best + sec + 1e-9f;
                route[token] = bi | (si << 8);
                gpair[token] = make_float2(best / s, sec / s);
            }
        }
    } else {
        // ---- pack half ----
        unsigned short* P = (unsigned short*)smem;   // [64*136] = 17.4 KB

        int b = blockIdx.x - 1024;
        int e  = b >> 7;
        int oy = (b & 127) >> 3;   // 0..15
        int dz = b & 7;            // 0..7
        int o0 = oy * 64, d0 = dz * 128;

#pragma unroll
        for (int r = 0; r < 32; ++r) {
            int lin = r * 256 + tid;
            int dd = lin >> 6, oo = lin & 63;
            P[oo * 136 + dd] = f2bf(We[((size_t)(e * D_ + d0 + dd)) * O_ + o0 + oo]);
        }
        __syncthreads();

#pragma unroll
        for (int w = 0; w < 4; ++w) {
            int ci = w * 256 + tid;      // 1024 16B-chunks
            int oo = ci >> 4, dc = ci & 15;
            uint4 v = *(const uint4*)&P[oo * 136 + dc * 8];
            int o = o0 + oo;
            int ot = o >> 7, nn = o & 127;
            unsigned short* dst =
                Wbp + ((size_t)((e * 8 + ot) * 128 + nn)) * D_ + d0 + dc * 8;
            *(uint4*)dst = v;
        }
    }
}

// ---------------------------------------------------------------------------
// Kernel 1b: deterministic stream compaction, one block per (t,e) group.
// 1024 threads: 4 serial chunk iterations instead of 16.
// toklist entry = n | (slot<<16); slot = 0 if e is token's primary expert.
// ---------------------------------------------------------------------------
__global__ __launch_bounds__(1024) void build_lists(
    const int* __restrict__ route, const float2* __restrict__ gpair,
    int* __restrict__ toklist, float* __restrict__ gatelist,
    int* __restrict__ counts)
{
    int g = blockIdx.x;              // t*8 + e
    int t = g >> 3, e = g & 7;
    int tid = threadIdx.x;
    int wave = tid >> 6, lane = tid & 63;

    __shared__ int waveSum[16];
    __shared__ int base;
    if (tid == 0) base = 0;

    for (int c = 0; c < N_; c += 1024) {
        int n = c + tid;
        int r = route[t * N_ + n];
        int e0 = r & 255, e1 = (r >> 8) & 255;
        bool sel = (e0 == e) || (e1 == e);
        unsigned long long b = __ballot(sel);
        int pre  = __popcll(b & ((1ull << lane) - 1ull));
        if (lane == 0) waveSum[wave] = __popcll(b);
        __syncthreads();
        int woff = 0, total = 0;
#pragma unroll
        for (int w = 0; w < 16; ++w) {
            int s = waveSum[w];
            total += s;
            woff += (w < wave) ? s : 0;
        }
        if (sel) {
            int p = base + woff + pre;
            int slot = (e0 == e) ? 0 : 1;
            toklist[g * N_ + p] = n | (slot << 16);
            float2 gp = gpair[t * N_ + n];
            gatelist[g * N_ + p] = (e0 == e) ? gp.x : gp.y;
        }
        __syncthreads();
        if (tid == 0) base += total;
    }
    __syncthreads();
    if (tid == 0) counts[g] = base;
}

// ---------------------------------------------------------------------------
// Kernel 3: grouped GEMM, round 14.
// r13 post-mortem: occupancy 16->45% at IDENTICAL 67us and MfmaUtil pinned
// at 21% -> NOT TLP-limited.  The invariant is the per-block serial chain:
// 32 K-steps x (s_barrier + vmcnt(0) drain + ds latency + 310cyc MFMA) with
// only ~4 real blocks/CU of depth.  m233: in a 2-phase loop the
// stage+vmcnt+barrier overhead is ~72% of the critical path.
// Single variable this round: BK 32->64 => 16 barrier/drain events (was 32).
// Per step/wave: 4 gld16 (8-row chunks of 128B contiguous per row -- also
// 2x fewer cache-line segments per instr than the old 16x64B gather),
// 12 ds_read_b128, 16 MFMA.  LDS 66.5KB -> 2 blocks/CU, 16 waves (~r13's
// realized occupancy => barrier count is the only moving part).
// Swizzle (8-row XOR, m201-style): LDS pos p of row r holds source granule
// p^(r&7); stage-side sg=(l&7)^(l>>3) (chunk=8 rows, granule=16B);
// read-side granule (q+4h)^(fr&7).  Per quarter-wave phase: 16 lanes over
// 8 granules = 2 lanes/bank = free (m136).
//  - mt-SLOWEST dispatch order + xcd = lin%8 kept.  1-D grid 4096.
// Falsifier (pre-committed): dur >= 63us => barrier count not binding ->
// pivot to staged-traffic elimination or 256^2 8-phase.
// ---------------------------------------------------------------------------
__global__ __launch_bounds__(512, 4) void moe_gemm(
    const unsigned short* __restrict__ xb,   // [T*N][D] bf16
    const unsigned short* __restrict__ Wbp,  // [(e*8+ot)*128+n][D] bf16
    const int* __restrict__ toklist, const float* __restrict__ gatelist,
    const int* __restrict__ counts, float* __restrict__ out)
{
    int lin = blockIdx.x;            // 0..4095
    int mt  = lin >> 7;              // slowest: real tiles (mt < ~9) first
    int u   = lin & 127;
    int xcd = u & 7;                 // == lin % 8 == hw XCD round-robin
    int v   = u >> 3;                // 0..15
    int g   = 2 * xcd + (v >> 3);    // xcd owns groups {2x, 2x+1}
    int ot  = v & 7;
    int t   = g >> 3;

    int cnt = counts[g];
    int m0 = mt * BM;
    if (m0 >= cnt) return;

    __shared__ __align__(16) unsigned short As[2][BM * BK];  // 32 KB
    __shared__ __align__(16) unsigned short Bs[2][BN * BK];  // 32 KB
    __shared__ int   tokS[BM];
    __shared__ float gateS[BM];

    int tid = threadIdx.x;
    if (tid < BM) {
        int r = m0 + tid;
        tokS[tid]  = (r < cnt) ? toklist[g * N_ + r]  : -1;
        gateS[tid] = (r < cnt) ? gatelist[g * N_ + r] : 0.f;
    }
    __syncthreads();

    int wave = tid >> 6, lane = tid & 63;   // 8 waves
    // staging: chunk = 8 rows x 128B (one BK=64 row-slice per row).
    // wave w stages chunks {2w, 2w+1} of A and of B (1 KB contiguous-per-row
    // each: 8 lines of 128B per gld16).  lane l -> row (l>>3) of chunk,
    // LDS granule (l&7); source granule sg = (l&7)^(l>>3), so LDS pos p of
    // row r holds granule p^(r&7)  (chunk base 8c: r&7 == l>>3).
    int cr = lane >> 3;                      // row within chunk 0..7
    int sg = (lane & 7) ^ cr;                // source 16B-granule to fetch
    int c0 = wave * 2, c1 = c0 + 1;
    int ar0 = c0 * 8 + cr, ar1 = c1 * 8 + cr;
    int tok0 = max(tokS[ar0], 0) & 0xFFFF;   // junk rows masked in epilogue
    int tok1 = max(tokS[ar1], 0) & 0xFFFF;
    const unsigned short* ag0 = xb + ((size_t)(t * N_ + tok0)) * D_ + sg * 8;
    const unsigned short* ag1 = xb + ((size_t)(t * N_ + tok1)) * D_ + sg * 8;
    const unsigned short* wb  = Wbp + ((size_t)((g & 7) * 8 + ot) * 128) * D_;
    const unsigned short* bg0 = wb + (size_t)ar0 * D_ + sg * 8;
    const unsigned short* bg1 = wb + (size_t)ar1 * D_ + sg * 8;

    int fr = lane & 15, q = lane >> 4;
    int wm = (wave & 1) * 64;                // 2 x 4 wave grid: 64 x 32 / wave
    int wn = (wave >> 1) * 32;
    int fx = fr & 7;                         // row&7 for the read-side XOR

    f32x4 acc[4][2];
#pragma unroll
    for (int mi = 0; mi < 4; ++mi)
#pragma unroll
        for (int ni = 0; ni < 2; ++ni) acc[mi][ni] = (f32x4){0.f, 0.f, 0.f, 0.f};

#define STAGE(BUF, KOFF)                                                       \
    {                                                                          \
        gld16(ag0 + (KOFF), &As[BUF][c0 * 512]);                               \
        gld16(ag1 + (KOFF), &As[BUF][c1 * 512]);                               \
        gld16(bg0 + (KOFF), &Bs[BUF][c0 * 512]);                               \
        gld16(bg1 + (KOFF), &Bs[BUF][c1 * 512]);                               \
    }

    // prologue: stage K-tile 0 into buffer 0
    STAGE(0, 0)

#define KSTEP(CUR, NXT, IT)                                                    \
    {                                                                          \
        __syncthreads(); /* drains vmcnt (tile IT landed) + NXT reads done */  \
        int k1 = ((IT) + 1) * BK;                                              \
        if (k1 < D_) STAGE(NXT, k1)                                            \
        short8 af[4][2], bf[2][2];                                             \
        _Pragma("unroll") for (int h = 0; h < 2; ++h) {                        \
            _Pragma("unroll") for (int mi = 0; mi < 4; ++mi)                   \
                af[mi][h] = *(const short8*)(                                  \
                    &As[CUR][(wm + mi * 16 + fr) * BK + (((q + 4 * h) ^ fx) * 8)]);\
            _Pragma("unroll") for (int ni = 0; ni < 2; ++ni)                   \
                bf[ni][h] = *(const short8*)(                                  \
                    &Bs[CUR][(wn + ni * 16 + fr) * BK + (((q + 4 * h) ^ fx) * 8)]);\
        }                                                                      \
        _Pragma("unroll") for (int h = 0; h < 2; ++h)                          \
            _Pragma("unroll") for (int mi = 0; mi < 4; ++mi)                   \
                _Pragma("unroll") for (int ni = 0; ni < 2; ++ni)               \
                    acc[mi][ni] = __builtin_amdgcn_mfma_f32_16x16x32_bf16(     \
                        af[mi][h], bf[ni][h], acc[mi][ni], 0, 0, 0);           \
    }

    for (int it = 0; it < D_ / BK; it += 2) {
        KSTEP(0, 1, it)
        KSTEP(1, 0, it + 1)
    }
#undef KSTEP
#undef STAGE

    // epilogue: C/D layout col = lane&15, row = q*4 + reg  [m89/m91]
    float* outb = out + (size_t)t * N_ * O_;
    int ncol = ot * 128 + wn + fr;
#pragma unroll
    for (int mi = 0; mi < 4; ++mi) {
#pragma unroll
        for (int r = 0; r < 4; ++r) {
            int ml = wm + mi * 16 + q * 4 + r;
            int ent = tokS[ml];
            if (ent >= 0) {
                int tokk = ent & 0xFFFF;
                int slot = ent >> 16;
                float gate = gateS[ml];
#pragma unroll
                for (int ni = 0; ni < 2; ++ni) {
                    unsigned short* p =
                        (unsigned short*)(outb + (size_t)tokk * O_ + ncol + ni * 16);
                    p[slot] = f2bf(gate * acc[mi][ni][r]);
                }
            }
        }
    }
}

// ---------------------------------------------------------------------------
// Kernel 4: combine the two bf16 slot halves of each out word into fp32.
// ---------------------------------------------------------------------------
__global__ __launch_bounds__(256) void combine_kernel(float* __restrict__ out)
{
    size_t i = ((size_t)blockIdx.x * 256 + threadIdx.x) * 4;
    unsigned* po = (unsigned*)out;
    uint4 v = *(uint4*)(po + i);
    float4 r;
    union { unsigned u; float f; } a, b;
#define CMB(comp, src) a.u = (src) << 16; b.u = (src) & 0xFFFF0000u; comp = a.f + b.f
    CMB(r.x, v.x); CMB(r.y, v.y); CMB(r.z, v.z); CMB(r.w, v.w);
#undef CMB
    *(float4*)(out + i) = r;
}

// ---------------------------------------------------------------------------
extern "C" void kernel_launch(void* const* d_in, const int* in_sizes, int n_in,
                              void* d_out, int out_size, void* d_ws, size_t ws_size,
                              hipStream_t stream)
{
    const float* x  = (const float*)d_in[0];
    const float* Wg = (const float*)d_in[1];
    const float* We = (const float*)d_in[2];
    float* out = (float*)d_out;

    char* ws = (char*)d_ws;
    unsigned short* xb   = (unsigned short*)(ws);               // 16,777,216 B
    unsigned short* Wbp  = (unsigned short*)(ws + 16777216);    // 16,777,216 B
    int*   toklist       = (int*)  (ws + 33554432);             //    262,144 B
    float* gatelist      = (float*)(ws + 33816576);             //    262,144 B
    int*   counts        = (int*)  (ws + 34078720);             //        256 B
    int*   route         = (int*)  (ws + 34078976);             //     32,768 B
    float2* gpair        = (float2*)(ws + 34111744);            //     65,536 B

    prep_kernel<<<2048, 256, 0, stream>>>(x, Wg, We, xb, Wbp, route, gpair);
    build_lists<<<T_ * E_, 1024, 0, stream>>>(route, gpair, toklist, gatelist, counts);
    moe_gemm<<<(N_ / BM) * 8 * (T_ * E_), 512, 0, stream>>>(
        xb, Wbp, toklist, gatelist, counts, out);
    combine_kernel<<<((size_t)T_ * N_ * O_) / (256 * 4), 256, 0, stream>>>(out);
}

// Round 7
// 177.533 us; speedup vs baseline: 1.0718x; 1.0718x over previous
//
#include <hip/hip_runtime.h>
#include <hip/hip_bf16.h>
#include <stdint.h>

#define T_ 2
#define N_ 4096
#define D_ 1024
#define E_ 8
#define O_ 1024

#define BM 128
#define BN 128
#define BK 32

typedef __attribute__((ext_vector_type(8))) short short8;
typedef __attribute__((ext_vector_type(4))) float f32x4;

#define AS1 __attribute__((address_space(1)))
#define AS3 __attribute__((address_space(3)))

// async global->LDS, 16B per lane; LDS dest = base + lane*16 (wave-uniform base)
__device__ inline void gld16(const unsigned short* g, unsigned short* l) {
    __builtin_amdgcn_global_load_lds((const AS1 unsigned int*)g,
                                     (AS3 unsigned int*)l, 16, 0, 0);
}

__device__ inline unsigned short f2bf(float f) {
    union { float f; unsigned u; } v; v.f = f;
    unsigned r = v.u + 0x7fff + ((v.u >> 16) & 1);  // RNE
    return (unsigned short)(r >> 16);
}

// ---------------------------------------------------------------------------
// Kernel 1 (fused): blocks 0..1023 = gating + x->bf16 (8 tokens/block);
// blocks 1024..2047 = We fp32 [e][d][o] -> bf16 in MFMA FRAGMENT ORDER:
//   Wf chunk index = (((e8*32 + ks)*8 + cb)*64 + lane), 8 bf16 per chunk,
//   e8 = e*8+ot, ks = k-step (k0=32ks), cb = 16-col block within ot,
//   lane = fr + 16q; value j = We[e][d = ks*32 + q*8 + j][o = ot*128+cb*16+fr].
// The GEMM then loads B fragments DIRECTLY global->reg, coalesced (64
// lanes x 16B consecutive), no LDS staging, no barrier participation.
// ---------------------------------------------------------------------------
__global__ __launch_bounds__(256) void prep_kernel(
    const float* __restrict__ x, const float* __restrict__ Wg,
    const float* __restrict__ We,
    unsigned short* __restrict__ xb, unsigned short* __restrict__ Wbp,
    int* __restrict__ route, float2* __restrict__ gpair)
{
    __shared__ __align__(16) char smem[E_ * D_ * 4];   // 32 KB (gate); pack uses 17.4 KB
    int tid = threadIdx.x;

    if (blockIdx.x < 1024) {
        // ---- gate half ----
        float (*WgT)[D_] = (float(*)[D_])smem;
        int wave = tid >> 6, lane = tid & 63;
        int token0 = blockIdx.x * 8;
        int t = token0 >> 12;                 // 8 consecutive tokens share t
        const float* wgb = Wg + (size_t)t * D_ * E_;

#pragma unroll
        for (int r = 0; r < 8; ++r) {
            int f = r * 1024 + tid * 4;       // flat Wg index; (d=f>>3, e=f&7)
            float4 v = *(const float4*)(wgb + f);
            WgT[f & 7][f >> 3]             = v.x;
            WgT[(f + 1) & 7][(f + 1) >> 3] = v.y;
            WgT[(f + 2) & 7][(f + 2) >> 3] = v.z;
            WgT[(f + 3) & 7][(f + 3) >> 3] = v.w;
        }
        __syncthreads();

#pragma unroll
        for (int tl = 0; tl < 2; ++tl) {
            int token = token0 + wave * 2 + tl;
            const float* xrow = x + (size_t)token * D_;

            float4 xv[4];
#pragma unroll
            for (int c = 0; c < 4; ++c)
                xv[c] = *(const float4*)(xrow + c * 256 + lane * 4);

            float acc[E_] = {0.f, 0.f, 0.f, 0.f, 0.f, 0.f, 0.f, 0.f};
#pragma unroll
            for (int c = 0; c < 4; ++c) {
                int d0 = c * 256 + lane * 4;
                unsigned lo = f2bf(xv[c].x) | ((unsigned)f2bf(xv[c].y) << 16);
                unsigned hi = f2bf(xv[c].z) | ((unsigned)f2bf(xv[c].w) << 16);
                *(uint2*)(&xb[(size_t)token * D_ + d0]) = make_uint2(lo, hi);
#pragma unroll
                for (int e = 0; e < E_; ++e) {
                    float4 w = *(const float4*)(&WgT[e][d0]);
                    acc[e] += xv[c].x * w.x + xv[c].y * w.y + xv[c].z * w.z + xv[c].w * w.w;
                }
            }
#pragma unroll
            for (int off = 1; off < 64; off <<= 1) {
#pragma unroll
                for (int e = 0; e < E_; ++e) acc[e] += __shfl_xor(acc[e], off, 64);
            }

            if (lane == 0) {
                // top-2, lowest-index-first on ties (matches jax.lax.top_k)
                float best = acc[0]; int bi = 0;
#pragma unroll
                for (int e = 1; e < E_; ++e) if (acc[e] > best) { best = acc[e]; bi = e; }
                float sec = -INFINITY; int si = 0;
#pragma unroll
                for (int e = 0; e < E_; ++e) if (e != bi && acc[e] > sec) { sec = acc[e]; si = e; }
                float s = best + sec + 1e-9f;
                route[token] = bi | (si << 8);
                gpair[token] = make_float2(best / s, sec / s);
            }
        }
    } else {
        // ---- pack half: fragment-order Wf ----
        unsigned short* P = (unsigned short*)smem;   // [64][136] = 17.4 KB

        int b = blockIdx.x - 1024;
        int e  = b >> 7;
        int oy = (b & 127) >> 3;   // 0..15  (o-block of 64)
        int dz = b & 7;            // 0..7   (d-block of 128)
        int o0 = oy * 64, d0 = dz * 128;

        // stage P[o_local 0..63][d_local 0..127], stride 136 (16B-aligned rows)
#pragma unroll
        for (int r = 0; r < 32; ++r) {
            int lin = r * 256 + tid;
            int dd = lin >> 6, oo = lin & 63;
            P[oo * 136 + dd] = f2bf(We[((size_t)(e * D_ + d0 + dd)) * O_ + o0 + oo]);
        }
        __syncthreads();

        // emit 1024 fragment chunks of 16B: ci -> (ks' 0..3, c16' 0..3, lane 0..63)
#pragma unroll
        for (int w = 0; w < 4; ++w) {
            int ci   = w * 256 + tid;
            int lane = ci & 63;
            int c16  = (ci >> 6) & 3;
            int ks   = ci >> 8;
            int fr = lane & 15, q = lane >> 4;
            uint4 v = *(const uint4*)&P[(c16 * 16 + fr) * 136 + ks * 32 + q * 8];
            int ot  = oy >> 1;
            int cb  = (oy * 4 + c16) & 7;
            int ksa = dz * 4 + ks;
            size_t idx = ((((size_t)(e * 8 + ot) * 32 + ksa) * 8 + cb) * 64 + lane) * 8;
            *(uint4*)(Wbp + idx) = v;
        }
    }
}

// ---------------------------------------------------------------------------
// Kernel 1b: deterministic stream compaction, one block per (t,e) group.
// 1024 threads: 4 serial chunk iterations instead of 16.
// toklist entry = n | (slot<<16); slot = 0 if e is token's primary expert.
// ---------------------------------------------------------------------------
__global__ __launch_bounds__(1024) void build_lists(
    const int* __restrict__ route, const float2* __restrict__ gpair,
    int* __restrict__ toklist, float* __restrict__ gatelist,
    int* __restrict__ counts)
{
    int g = blockIdx.x;              // t*8 + e
    int t = g >> 3, e = g & 7;
    int tid = threadIdx.x;
    int wave = tid >> 6, lane = tid & 63;

    __shared__ int waveSum[16];
    __shared__ int base;
    if (tid == 0) base = 0;

    for (int c = 0; c < N_; c += 1024) {
        int n = c + tid;
        int r = route[t * N_ + n];
        int e0 = r & 255, e1 = (r >> 8) & 255;
        bool sel = (e0 == e) || (e1 == e);
        unsigned long long b = __ballot(sel);
        int pre  = __popcll(b & ((1ull << lane) - 1ull));
        if (lane == 0) waveSum[wave] = __popcll(b);
        __syncthreads();
        int woff = 0, total = 0;
#pragma unroll
        for (int w = 0; w < 16; ++w) {
            int s = waveSum[w];
            total += s;
            woff += (w < wave) ? s : 0;
        }
        if (sel) {
            int p = base + woff + pre;
            int slot = (e0 == e) ? 0 : 1;
            toklist[g * N_ + p] = n | (slot << 16);
            float2 gp = gpair[t * N_ + n];
            gatelist[g * N_ + p] = (e0 == e) ? gp.x : gp.y;
        }
        __syncthreads();
        if (tid == 0) base += total;
    }
    __syncthreads();
    if (tid == 0) counts[g] = base;
}

// ---------------------------------------------------------------------------
// Kernel 3: grouped GEMM, round 15.
// r13/r14 post-mortem: occupancy x2 (null) and barrier-count /2 (regression)
// both failed -> every pipe <50% busy; the serialized
// {stage -> vmcnt(0) drain -> ds_read -> MFMA} chain IS the limit (m233:
// 72% structural overhead in 2-phase loops).  This round removes B from the
// chain entirely:
//  - B comes fragment-packed from prep (chunk = exactly one lane's 16B),
//    loaded global->REGISTER, coalesced 1KB/wave-instr, prefetched ONE FULL
//    K-STEP ahead; it never touches LDS and never waits on the barrier.
//    Compiler auto-inserts the counted vmcnt before MFMA use (register dep).
//  - A (token-gather) still LDS-staged, 1 gld16/wave/step, double-buffered.
//    The barrier wait is now a counted vmcnt(2): per step we issue exactly
//    [A-gld16, fence, B0, B1]; A is the OLDEST of the 3 outstanding ->
//    vmcnt(2) proves A landed.  NO vmcnt(0) in the main loop (T4/m218).
//    Issue order A-before-B pinned by an asm memory-clobber fence.
//  - 2-buffer safety w/ one barrier per step: step t's ds_reads complete
//    (lgkm-waited before MFMA) before barrier(t+1), so the gld16(t+1) write
//    to the buffer read at t cannot race it.
// Per step/wave: 1 gld16 + 2 reg-loads + 4 ds_read_b128 + 8 MFMA
// (was 2 gld16 + 6 ds_read + 8 MFMA + full drain).  LDS 17.4 KB.
//  - quarter-phase A swizzle kept (0 conflicts, r9-verified).
//  - mt-SLOWEST dispatch order + xcd = lin%8 kept.  1-D grid 4096.
// Falsifier: >= 60us -> port m201 8-phase 256^2 template next.
// ---------------------------------------------------------------------------
__global__ __launch_bounds__(512, 4) void moe_gemm(
    const unsigned short* __restrict__ xb,   // [T*N][D] bf16
    const unsigned short* __restrict__ Wbp,  // fragment-order Wf (see prep)
    const int* __restrict__ toklist, const float* __restrict__ gatelist,
    const int* __restrict__ counts, float* __restrict__ out)
{
    int lin = blockIdx.x;            // 0..4095
    int mt  = lin >> 7;              // slowest: real tiles (mt < ~9) first
    int u   = lin & 127;
    int xcd = u & 7;                 // == lin % 8 == hw XCD round-robin
    int v   = u >> 3;                // 0..15
    int g   = 2 * xcd + (v >> 3);    // xcd owns groups {2x, 2x+1}
    int ot  = v & 7;
    int t   = g >> 3;

    int cnt = counts[g];
    int m0 = mt * BM;
    if (m0 >= cnt) return;

    __shared__ __align__(16) unsigned short As[2][BM * BK];  // 16 KB
    __shared__ int   tokS[BM];
    __shared__ float gateS[BM];

    int tid = threadIdx.x;
    if (tid < BM) {
        int r = m0 + tid;
        tokS[tid]  = (r < cnt) ? toklist[g * N_ + r]  : -1;
        gateS[tid] = (r < cnt) ? gatelist[g * N_ + r] : 0.f;
    }
    __syncthreads();   // queues drained entering the pipeline

    int wave = tid >> 6, lane = tid & 63;   // 8 waves
    // A staging: wave w stages 16-row chunk w (rows 16w..16w+15), 1 KB.
    // lane l -> row (l>>2) of chunk, LDS granule (l&3); source granule
    // sg = (l&3)^((l>>3)&3): LDS pos p of row r holds granule p^((r>>1)&3).
    int lr = lane >> 2;
    int sg = (lane & 3) ^ ((lane >> 3) & 3);
    int ar = wave * 16 + lr;
    int tok = max(tokS[ar], 0) & 0xFFFF;     // junk rows masked in epilogue
    const unsigned short* ag = xb + ((size_t)(t * N_ + tok)) * D_ + sg * 8;

    // B fragment pointers: e8 = (g&7)*8+ot; per-ks stride 4096 shorts;
    // per-cb stride 512; lane offset lane*8.
    const unsigned short* wf =
        Wbp + ((size_t)((g & 7) * 8 + ot) * 32) * 4096;
    int cb0 = (wave >> 1) * 2;
    const unsigned short* bp0 = wf + cb0 * 512 + lane * 8;
    const unsigned short* bp1 = bp0 + 512;

    int fr = lane & 15, q = lane >> 4;
    int wm = (wave & 1) * 64;                // 2 x 4 wave grid: 64 x 32 / wave
    int wn = (wave >> 1) * 32;
    int fp = (q ^ ((fr >> 1) & 3)) * 8;      // read-side swizzled granule

    f32x4 acc[4][2];
#pragma unroll
    for (int mi = 0; mi < 4; ++mi)
#pragma unroll
        for (int ni = 0; ni < 2; ++ni) acc[mi][ni] = (f32x4){0.f, 0.f, 0.f, 0.f};

    short8 bf0[2], bf1[2];

    // prologue: A(0) then (fence) B(0) -- order pins A oldest in the queue
    gld16(ag, &As[0][wave * 512]);
    asm volatile("" ::: "memory");
    bf0[0] = *(const short8*)(bp0);
    bf0[1] = *(const short8*)(bp1);

#define KSTEP(CUR, NXT, BC, BNX, IT)                                           \
    {                                                                          \
        asm volatile("s_waitcnt vmcnt(2)" ::: "memory"); /* A(IT) landed */    \
        __builtin_amdgcn_s_barrier();                                          \
        asm volatile("" ::: "memory");   /* no LDS ops cross the barrier */    \
        int kk = (IT) + 1;                                                     \
        if (kk < D_ / BK) {                                                    \
            gld16(ag + (size_t)kk * BK, &As[NXT][wave * 512]);                 \
            asm volatile("" ::: "memory");  /* pin A-before-B issue order */   \
            BNX[0] = *(const short8*)(bp0 + (size_t)kk * 4096);                \
            BNX[1] = *(const short8*)(bp1 + (size_t)kk * 4096);                \
        }                                                                      \
        short8 af[4];                                                          \
        _Pragma("unroll") for (int mi = 0; mi < 4; ++mi)                       \
            af[mi] = *(const short8*)(&As[CUR][(wm + mi * 16 + fr) * BK + fp]);\
        _Pragma("unroll") for (int mi = 0; mi < 4; ++mi) {                     \
            acc[mi][0] = __builtin_amdgcn_mfma_f32_16x16x32_bf16(              \
                af[mi], BC[0], acc[mi][0], 0, 0, 0);                           \
            acc[mi][1] = __builtin_amdgcn_mfma_f32_16x16x32_bf16(              \
                af[mi], BC[1], acc[mi][1], 0, 0, 0);                           \
        }                                                                      \
    }

    for (int it = 0; it < D_ / BK; it += 2) {
        KSTEP(0, 1, bf0, bf1, it)
        KSTEP(1, 0, bf1, bf0, it + 1)
    }
#undef KSTEP

    // epilogue: C/D layout col = lane&15, row = q*4 + reg  [m89/m91]
    float* outb = out + (size_t)t * N_ * O_;
    int ncol = ot * 128 + wn + fr;
#pragma unroll
    for (int mi = 0; mi < 4; ++mi) {
#pragma unroll
        for (int r = 0; r < 4; ++r) {
            int ml = wm + mi * 16 + q * 4 + r;
            int ent = tokS[ml];
            if (ent >= 0) {
                int tokk = ent & 0xFFFF;
                int slot = ent >> 16;
                float gate = gateS[ml];
#pragma unroll
                for (int ni = 0; ni < 2; ++ni) {
                    unsigned short* p =
                        (unsigned short*)(outb + (size_t)tokk * O_ + ncol + ni * 16);
                    p[slot] = f2bf(gate * acc[mi][ni][r]);
                }
            }
        }
    }
}

// ---------------------------------------------------------------------------
// Kernel 4: combine the two bf16 slot halves of each out word into fp32.
// ---------------------------------------------------------------------------
__global__ __launch_bounds__(256) void combine_kernel(float* __restrict__ out)
{
    size_t i = ((size_t)blockIdx.x * 256 + threadIdx.x) * 4;
    unsigned* po = (unsigned*)out;
    uint4 v = *(uint4*)(po + i);
    float4 r;
    union { unsigned u; float f; } a, b;
#define CMB(comp, src) a.u = (src) << 16; b.u = (src) & 0xFFFF0000u; comp = a.f + b.f
    CMB(r.x, v.x); CMB(r.y, v.y); CMB(r.z, v.z); CMB(r.w, v.w);
#undef CMB
    *(float4*)(out + i) = r;
}

// ---------------------------------------------------------------------------
extern "C" void kernel_launch(void* const* d_in, const int* in_sizes, int n_in,
                              void* d_out, int out_size, void* d_ws, size_t ws_size,
                              hipStream_t stream)
{
    const float* x  = (const float*)d_in[0];
    const float* Wg = (const float*)d_in[1];
    const float* We = (const float*)d_in[2];
    float* out = (float*)d_out;

    char* ws = (char*)d_ws;
    unsigned short* xb   = (unsigned short*)(ws);               // 16,777,216 B
    unsigned short* Wbp  = (unsigned short*)(ws + 16777216);    // 16,777,216 B
    int*   toklist       = (int*)  (ws + 33554432);             //    262,144 B
    float* gatelist      = (float*)(ws + 33816576);             //    262,144 B
    int*   counts        = (int*)  (ws + 34078720);             //        256 B
    int*   route         = (int*)  (ws + 34078976);             //     32,768 B
    float2* gpair        = (float2*)(ws + 34111744);            //     65,536 B

    prep_kernel<<<2048, 256, 0, stream>>>(x, Wg, We, xb, Wbp, route, gpair);
    build_lists<<<T_ * E_, 1024, 0, stream>>>(route, gpair, toklist, gatelist, counts);
    moe_gemm<<<(N_ / BM) * 8 * (T_ * E_), 512, 0, stream>>>(
        xb, Wbp, toklist, gatelist, counts, out);
    combine_kernel<<<((size_t)T_ * N_ * O_) / (256 * 4), 256, 0, stream>>>(out);
}